// Round 8
// baseline (407.936 us; speedup 1.0000x reference)
//
#include <hip/hip_runtime.h>
#include <math.h>

#define E_DIM 64
#define N_E   1024
#define BETA  0.25

using bf16x8 = __attribute__((ext_vector_type(8))) short;
using f32x4  = __attribute__((ext_vector_type(4))) float;
#define MFMA(a, b, c) __builtin_amdgcn_mfma_f32_16x16x32_bf16((a), (b), (c), 0, 0, 0)

// ---------------------------------------------------------------------------
// Numerics contract (idx must match the fp32 numpy reference exactly):
//   exact score_j = h_j - m_ij, m = sequential fp32 FMA chain (round-3 proven)
//   MFMA path: s~_j = h_j - [2z]_hi/lo x [e]_hi/lo (3 bf16 MFMA terms, fp32 acc)
//     |s~ - score| <= eps_row = 3*2^-18 * (2/1024)*Sum|z_k| + acc-rounding
//   Rows with (2nd-best - best) <= Delta_row = 2*eps_row + 2.2e-5 are flagged
//   and re-resolved with the exact round-3 scan (also handles MFMA-layout
//   self-test failure: all rows flagged -> slow-but-correct).
//
// ws: [0,4096) hist | [4096] sse f64 | [4104] flagN u32 | [4112,8208) h f32
//     [8208) ebh bf16[65536] | [139280) ebl | [270352) flagL u32[65536]
// ---------------------------------------------------------------------------

__device__ __forceinline__ unsigned short f2bf_rn(float f) {
    unsigned u = __builtin_bit_cast(unsigned, f);
    unsigned r = u + 0x7fffu + ((u >> 16) & 1u);
    return (unsigned short)(r >> 16);
}
__device__ __forceinline__ float bf2f(unsigned short b) {
    unsigned u = ((unsigned)b) << 16;
    return __builtin_bit_cast(float, u);
}

__device__ __forceinline__ float pw64_sq(const float* v) {
    float r[8];
#pragma unroll
    for (int l = 0; l < 8; ++l) r[l] = v[l] * v[l];
#pragma unroll
    for (int t = 1; t < 8; ++t)
#pragma unroll
        for (int l = 0; l < 8; ++l) r[l] += v[8 * t + l] * v[8 * t + l];
    return ((r[0] + r[1]) + (r[2] + r[3])) + ((r[4] + r[5]) + (r[6] + r[7]));
}

__global__ __launch_bounds__(256) void k_h(const float* __restrict__ cb,
                                           float* __restrict__ h) {
    int j = blockIdx.x * 256 + threadIdx.x;
    if (j < N_E) {
        float e[E_DIM];
        const float4* ep = reinterpret_cast<const float4*>(cb + (size_t)j * E_DIM);
#pragma unroll
        for (int k4 = 0; k4 < E_DIM / 4; ++k4) {
            float4 v = ep[k4];
            e[4 * k4 + 0] = v.x; e[4 * k4 + 1] = v.y;
            e[4 * k4 + 2] = v.z; e[4 * k4 + 3] = v.w;
        }
        h[j] = pw64_sq(e);
    }
}

// Pack codebook into MFMA B-fragment order (bf16 hi/lo split).
// Linear t = ct*1024 + ks*512 + lane*8 + e  <->  B[k][n]: n=lane&15, k=ks*32+(lane>>4)*8+e
__global__ __launch_bounds__(256) void k_prep(const float* __restrict__ cb,
                                              unsigned short* __restrict__ ebh,
                                              unsigned short* __restrict__ ebl) {
    int t = blockIdx.x * 256 + threadIdx.x;
    int e = t & 7, lane = (t >> 3) & 63, ks = (t >> 9) & 1, ct = t >> 10;
    int j = ct * 16 + (lane & 15);
    int k = ks * 32 + ((lane >> 4) << 3) + e;
    float v = cb[j * 64 + k];
    unsigned short hi = f2bf_rn(v);
    ebh[t] = hi;
    ebl[t] = f2bf_rn(v - bf2f(hi));
}

// Block = 4 waves x 64 lanes; wave = one 16-row tile x all 1024 codes.
__global__ __launch_bounds__(256, 4) void k_mfma(
    const float* __restrict__ z, const float* __restrict__ cb,
    const float* __restrict__ h,
    const unsigned short* __restrict__ ebh, const unsigned short* __restrict__ ebl,
    float* __restrict__ out_zq, float* __restrict__ out_idx,
    unsigned* __restrict__ hist, double* __restrict__ sse,
    unsigned* __restrict__ flagN, unsigned* __restrict__ flagL) {
    const int lane = threadIdx.x & 63;
    const int w = __builtin_amdgcn_readfirstlane(threadIdx.x >> 6);
    const int m = lane & 15, g = lane >> 4;

    __shared__ int bok;
    __shared__ float rs[4][16];
    if (threadIdx.x == 0) bok = 1;
    __syncthreads();

    // ---- MFMA layout self-test (asymmetric integer patterns, exact) ----
    {
        bf16x8 a, b;
#pragma unroll
        for (int e = 0; e < 8; ++e) {
            int k = g * 8 + e;
            a[e] = (short)f2bf_rn((float)(((m * 3 + k * 7) & 15) - 7));
            b[e] = (short)f2bf_rn((float)(((k * 5 + m * 3) & 15) - 8));
        }
        f32x4 acc = {0.f, 0.f, 0.f, 0.f};
        acc = MFMA(a, b, acc);
        bool ok = true;
#pragma unroll
        for (int r = 0; r < 4; ++r) {
            int rw = g * 4 + r;
            float E = 0.f;
            for (int k = 0; k < 32; ++k)
                E += (float)((((rw * 3 + k * 7) & 15) - 7) * (((k * 5 + m * 3) & 15) - 8));
            ok = ok && (acc[r] == E);
        }
        if (!ok) atomicAnd(&bok, 0);
    }
    __syncthreads();
    if (!bok) {   // layout assumption wrong: defer whole block to exact cleanup
        if (threadIdx.x < 64) {
            unsigned p = atomicAdd(flagN, 1u);
            flagL[p] = (unsigned)(blockIdx.x * 64 + threadIdx.x);
        }
        return;
    }

    // ---- A-load: z rows, hi/lo split of 2z, and per-row Sum|z| ----
    const int rowb = blockIdx.x * 64 + w * 16;
    const int rowA = rowb + m;
    const float4* zr = reinterpret_cast<const float4*>(z + (size_t)rowA * 64);
    float4 p0 = zr[g * 2], p1 = zr[g * 2 + 1], p2 = zr[8 + g * 2], p3 = zr[9 + g * 2];
    bf16x8 ah0, al0, ah1, al1;
    {
        float t0[8] = {p0.x, p0.y, p0.z, p0.w, p1.x, p1.y, p1.z, p1.w};
        float t1[8] = {p2.x, p2.y, p2.z, p2.w, p3.x, p3.y, p3.z, p3.w};
        float s = 0.f;
#pragma unroll
        for (int e = 0; e < 8; ++e) {
            s += fabsf(t0[e]) + fabsf(t1[e]);
            float a0 = 2.0f * t0[e]; unsigned short h0 = f2bf_rn(a0);
            ah0[e] = (short)h0; al0[e] = (short)f2bf_rn(a0 - bf2f(h0));
            float a1 = 2.0f * t1[e]; unsigned short h1 = f2bf_rn(a1);
            ah1[e] = (short)h1; al1[e] = (short)f2bf_rn(a1 - bf2f(h1));
        }
        s += __shfl_xor(s, 16);
        s += __shfl_xor(s, 32);
        if (g == 0) rs[w][m] = s;
    }

    // ---- scan: 64 col-tiles, best-2 tracking per row-slot ----
    float b00 = INFINITY, b01 = INFINITY, b02 = INFINITY, b03 = INFINITY;
    float b10 = INFINITY, b11 = INFINITY, b12 = INFINITY, b13 = INFINITY;
    int   i00 = 0, i01 = 0, i02 = 0, i03 = 0;
    const bf16x8* pBh = reinterpret_cast<const bf16x8*>(ebh);
    const bf16x8* pBl = reinterpret_cast<const bf16x8*>(ebl);
#pragma unroll 1
    for (int ct = 0; ct < 64; ++ct) {
        const int fb = ct * 128 + lane;
        bf16x8 vbh0 = pBh[fb], vbh1 = pBh[fb + 64];
        bf16x8 vbl0 = pBl[fb], vbl1 = pBl[fb + 64];
        f32x4 acc1 = {0.f, 0.f, 0.f, 0.f}, acc2 = {0.f, 0.f, 0.f, 0.f};
        acc1 = MFMA(ah0, vbh0, acc1);
        acc2 = MFMA(ah1, vbh1, acc2);
        acc1 = MFMA(ah0, vbl0, acc1);
        acc2 = MFMA(ah1, vbl1, acc2);
        acc1 = MFMA(al0, vbh0, acc1);
        acc2 = MFMA(al1, vbh1, acc2);
        const int j = ct * 16 + m;
        const float hj = h[j];
        float s0 = hj - (acc1[0] + acc2[0]);
        float s1 = hj - (acc1[1] + acc2[1]);
        float s2 = hj - (acc1[2] + acc2[2]);
        float s3 = hj - (acc1[3] + acc2[3]);
        if (s0 < b00) { b10 = b00; b00 = s0; i00 = j; } else b10 = fminf(b10, s0);
        if (s1 < b01) { b11 = b01; b01 = s1; i01 = j; } else b11 = fminf(b11, s1);
        if (s2 < b02) { b12 = b02; b02 = s2; i02 = j; } else b12 = fminf(b12, s2);
        if (s3 < b03) { b13 = b03; b03 = s3; i03 = j; } else b13 = fminf(b13, s3);
    }

    // ---- reduce best/2nd across the 16 col-lanes of each group ----
#pragma unroll
    for (int mask = 1; mask < 16; mask <<= 1) {
#define MRG(B0, I0, B1) { float ob0 = __shfl_xor(B0, mask); int oi = __shfl_xor(I0, mask); \
        float ob1 = __shfl_xor(B1, mask); \
        if (ob0 < B0) { B1 = fminf(fminf(B0, B1), ob1); B0 = ob0; I0 = oi; } \
        else { B1 = fminf(B1, fminf(ob0, ob1)); } }
        MRG(b00, i00, b10) MRG(b01, i01, b11) MRG(b02, i02, b12) MRG(b03, i03, b13)
#undef MRG
    }

    // ---- epilogue: 4 lanes per row (r = m>>2, q = m&3) ----
    const int r = m >> 2, q = m & 3;
    float vb0 = (r == 0) ? b00 : (r == 1) ? b01 : (r == 2) ? b02 : b03;
    float vb1 = (r == 0) ? b10 : (r == 1) ? b11 : (r == 2) ? b12 : b13;
    int   vi  = (r == 0) ? i00 : (r == 1) ? i01 : (r == 2) ? i02 : i03;
    const int rloc = g * 4 + r;
    const int rowO = rowb + rloc;
    const float Delta = 6e-8f * rs[w][rloc] + 2.2e-5f;
    float local = 0.f;
    if (vb1 - vb0 <= Delta) {
        if (q == 0) { unsigned p = atomicAdd(flagN, 1u); flagL[p] = (unsigned)rowO; }
    } else {
        if (q == 0) { out_idx[rowO] = (float)vi; atomicAdd(&hist[vi], 1u); }
        const float4* cv = reinterpret_cast<const float4*>(cb + (size_t)vi * 64) + q * 4;
        const float4* zv = reinterpret_cast<const float4*>(z + (size_t)rowO * 64) + q * 4;
        float* orow = out_zq + (size_t)rowO * 64 + q * 16;
#pragma unroll
        for (int u = 0; u < 4; ++u) {
            float4 cc = cv[u], zz = zv[u];
            orow[4 * u + 0] = cc.x; orow[4 * u + 1] = cc.y;
            orow[4 * u + 2] = cc.z; orow[4 * u + 3] = cc.w;
            float dx = cc.x - zz.x, dy = cc.y - zz.y;
            float dz = cc.z - zz.z, dw = cc.w - zz.w;
            local = fmaf(dx, dx, local); local = fmaf(dy, dy, local);
            local = fmaf(dz, dz, local); local = fmaf(dw, dw, local);
        }
    }
#pragma unroll
    for (int off = 32; off; off >>= 1) local += __shfl_down(local, off);
    if (lane == 0) atomicAdd(sse, (double)local);
}

// Exact round-3 re-scan for flagged rows (bit-identical to the passing kernel).
__global__ __launch_bounds__(64, 4) void k_cleanup(
    const float* __restrict__ z, const float* __restrict__ cb,
    const float* __restrict__ h,
    const unsigned* __restrict__ flagN, const unsigned* __restrict__ flagL,
    float* __restrict__ out_zq, float* __restrict__ out_idx,
    unsigned* __restrict__ hist, double* __restrict__ sse) {
    const unsigned n = *flagN;
    float total = 0.f;
    for (unsigned f = blockIdx.x * 64 + threadIdx.x; f < n; f += gridDim.x * 64) {
        const int row = (int)flagL[f];
        float tz[E_DIM];
        const float4* zp = reinterpret_cast<const float4*>(z + (size_t)row * 64);
#pragma unroll
        for (int k4 = 0; k4 < 16; ++k4) {
            float4 v = zp[k4];
            tz[4 * k4 + 0] = v.x; tz[4 * k4 + 1] = v.y;
            tz[4 * k4 + 2] = v.z; tz[4 * k4 + 3] = v.w;
        }
        const float nz = pw64_sq(tz);
#pragma unroll
        for (int k = 0; k < 64; ++k) tz[k] = 2.0f * tz[k];
        float b = INFINITY; int bi = 0;
#pragma unroll 1
        for (int j = 0; j < N_E; ++j) {       // uniform j -> s_load; ascending strict <
            const float* c0 = cb + (size_t)j * 64;
            float mm = 0.f;
#pragma unroll
            for (int k = 0; k < 64; ++k) mm = fmaf(tz[k], c0[k], mm);
            float s = (nz + h[j]) - mm;
            if (s < b) { b = s; bi = j; }
        }
        out_idx[row] = (float)bi;
        atomicAdd(&hist[bi], 1u);
        float local = 0.f;
        float* orow = out_zq + (size_t)row * 64;
        const float* cc = cb + (size_t)bi * 64;
#pragma unroll
        for (int k = 0; k < 64; ++k) {
            float cv = cc[k];
            orow[k] = cv;
            float d = cv - 0.5f * tz[k];
            local = fmaf(d, d, local);
        }
        total += local;
    }
#pragma unroll
    for (int off = 32; off; off >>= 1) total += __shfl_down(total, off);
    if (threadIdx.x == 0 && total != 0.f) atomicAdd(sse, (double)total);
}

// ---- round-5 fallback scan (used only if ws_size is too small) ----
__global__ __launch_bounds__(512, 2) void k_scan_fb(
    const float* __restrict__ z, const float* __restrict__ cb,
    const float* __restrict__ h,
    float* __restrict__ out_zq, float* __restrict__ out_idx,
    unsigned* __restrict__ hist, double* __restrict__ sse) {
    const int lane = threadIdx.x & 63;
    const int w = __builtin_amdgcn_readfirstlane(threadIdx.x >> 6);
    const int row = blockIdx.x * 64 + lane;
    float tz[E_DIM];
    const float4* zp = reinterpret_cast<const float4*>(z + (size_t)row * E_DIM);
#pragma unroll
    for (int k4 = 0; k4 < E_DIM / 4; ++k4) {
        float4 v = zp[k4];
        tz[4 * k4 + 0] = v.x; tz[4 * k4 + 1] = v.y;
        tz[4 * k4 + 2] = v.z; tz[4 * k4 + 3] = v.w;
    }
    const float nz = pw64_sq(tz);
#pragma unroll
    for (int k = 0; k < E_DIM; ++k) tz[k] = 2.0f * tz[k];
    float b0 = INFINITY; int bi = 0;
    const int j0 = w * 128;
#pragma unroll 1
    for (int j = j0; j < j0 + 128; j += 4) {
        const float* c0 = cb + (size_t)j * E_DIM;
        float m0 = 0.f, m1 = 0.f, m2 = 0.f, m3 = 0.f;
#pragma unroll
        for (int k = 0; k < E_DIM; ++k) {
            float wk = tz[k];
            m0 = fmaf(wk, c0[0 * E_DIM + k], m0);
            m1 = fmaf(wk, c0[1 * E_DIM + k], m1);
            m2 = fmaf(wk, c0[2 * E_DIM + k], m2);
            m3 = fmaf(wk, c0[3 * E_DIM + k], m3);
        }
        float s0 = (nz + h[j + 0]) - m0;
        float s1 = (nz + h[j + 1]) - m1;
        float s2 = (nz + h[j + 2]) - m2;
        float s3 = (nz + h[j + 3]) - m3;
        if (s0 < b0) { b0 = s0; bi = j + 0; }
        if (s1 < b0) { b0 = s1; bi = j + 1; }
        if (s2 < b0) { b0 = s2; bi = j + 2; }
        if (s3 < b0) { b0 = s3; bi = j + 3; }
    }
    __shared__ float lb[8][64];
    __shared__ int   li[8][64];
    lb[w][lane] = b0; li[w][lane] = bi;
    __syncthreads();
    if (threadIdx.x < 64) {
        float b = lb[0][lane]; int i = li[0][lane];
#pragma unroll
        for (int c = 1; c < 8; ++c) {
            float bc = lb[c][lane]; int ic = li[c][lane];
            if (bc < b) { b = bc; i = ic; }
        }
        out_idx[row] = (float)i;
        float local = 0.f;
        const float4* cv = reinterpret_cast<const float4*>(cb + (size_t)i * E_DIM);
        float* orow = out_zq + (size_t)row * E_DIM;
#pragma unroll
        for (int k4 = 0; k4 < E_DIM / 4; ++k4) {
            float4 c = cv[k4];
            float zx = 0.5f * tz[4 * k4 + 0], zy = 0.5f * tz[4 * k4 + 1];
            float zz = 0.5f * tz[4 * k4 + 2], zw = 0.5f * tz[4 * k4 + 3];
            orow[4 * k4 + 0] = c.x; orow[4 * k4 + 1] = c.y;
            orow[4 * k4 + 2] = c.z; orow[4 * k4 + 3] = c.w;
            float dx = c.x - zx, dy = c.y - zy, dz = c.z - zz, dw = c.w - zw;
            local = fmaf(dx, dx, local); local = fmaf(dy, dy, local);
            local = fmaf(dz, dz, local); local = fmaf(dw, dw, local);
        }
        atomicAdd(&hist[i], 1u);
#pragma unroll
        for (int off = 32; off; off >>= 1) local += __shfl_down(local, off);
        if (lane == 0) atomicAdd(sse, (double)local);
    }
}

__global__ __launch_bounds__(256) void k_final(
    const unsigned* __restrict__ hist, const double* __restrict__ sse,
    float* __restrict__ out, int nrows) {
    __shared__ double sh[256];
    double acc = 0.0;
    for (int j = threadIdx.x; j < N_E; j += 256) {
        double p = (double)hist[j] / (double)nrows;
        acc += p * log(p + 1e-10);
    }
    sh[threadIdx.x] = acc;
    __syncthreads();
    for (int s = 128; s; s >>= 1) {
        if (threadIdx.x < s) sh[threadIdx.x] += sh[threadIdx.x + s];
        __syncthreads();
    }
    if (threadIdx.x == 0) {
        double ntot = (double)nrows * (double)E_DIM;
        out[0] = (float)((1.0 + BETA) * (*sse) / ntot);               // loss
        out[1 + (size_t)nrows * E_DIM] = (float)exp(-sh[0]);          // perplexity
    }
}

extern "C" void kernel_launch(void* const* d_in, const int* in_sizes, int n_in,
                              void* d_out, int out_size, void* d_ws, size_t ws_size,
                              hipStream_t stream) {
    const float* z  = (const float*)d_in[0];
    const float* cb = (const float*)d_in[1];
    const int nrows = in_sizes[0] / E_DIM;   // 65536
    float* out = (float*)d_out;

    char* ws = (char*)d_ws;
    unsigned* hist  = (unsigned*)(ws + 0);
    double*   sse   = (double*)  (ws + 4096);
    unsigned* flagN = (unsigned*)(ws + 4104);
    float*    h     = (float*)   (ws + 4112);
    unsigned short* ebh = (unsigned short*)(ws + 8208);
    unsigned short* ebl = (unsigned short*)(ws + 139280);
    unsigned* flagL = (unsigned*)(ws + 270352);
    // end of ws use: 270352 + 262144 = 532496 bytes

    float* out_zq  = out + 1;
    float* out_idx = out + 1 + (size_t)nrows * E_DIM + 1;

    hipMemsetAsync(d_ws, 0, 4112, stream);  // hist + sse + flagN
    k_h<<<(N_E + 255) / 256, 256, 0, stream>>>(cb, h);

    if (ws_size >= 532496) {
        k_prep<<<256, 256, 0, stream>>>(cb, ebh, ebl);
        k_mfma<<<nrows / 64, 256, 0, stream>>>(z, cb, h, ebh, ebl,
                                               out_zq, out_idx, hist, sse, flagN, flagL);
        k_cleanup<<<1024, 64, 0, stream>>>(z, cb, h, flagN, flagL,
                                           out_zq, out_idx, hist, sse);
    } else {
        k_scan_fb<<<nrows / 64, 512, 0, stream>>>(z, cb, h, out_zq, out_idx, hist, sse);
    }
    k_final<<<1, 256, 0, stream>>>(hist, sse, out, nrows);
}

// Round 9
// 149.910 us; speedup vs baseline: 2.7212x; 2.7212x over previous
//
#include <hip/hip_runtime.h>
#include <math.h>

#define E_DIM 64
#define N_E   1024
#define BETA  0.25

using bf16x8 = __attribute__((ext_vector_type(8))) short;
using f32x4  = __attribute__((ext_vector_type(4))) float;
#define MFMA(a, b, c) __builtin_amdgcn_mfma_f32_16x16x32_bf16((a), (b), (c), 0, 0, 0)

// ---------------------------------------------------------------------------
// Numerics contract (idx must match the fp32 numpy reference exactly):
//   exact score_j = h_j - m_ij, m = sequential fp32 FMA chain (round-3 proven)
//   MFMA path: s~_j = h_j - [2z]_hi/lo x [e]_hi/lo (3 bf16 MFMA terms, fp32 acc)
//   Rows with (2nd-best - best) <= Delta_row are flagged and re-resolved with
//   the exact round-3 chain by k_cleanup (one WAVE per row, 16 codes/lane —
//   chain value is lane-placement-invariant; cross-lane tie-break on lower j
//   == np.argmin first-occurrence).
//
// ws: [0,4096) hist | [4096] sse f64 | [4104] flagN u32 | [4112,8208) h f32
//     [8208) ebh bf16[65536] | [139280) ebl | [270352) flagL u32[65536]
// ---------------------------------------------------------------------------

__device__ __forceinline__ unsigned short f2bf_rn(float f) {
    unsigned u = __builtin_bit_cast(unsigned, f);
    unsigned r = u + 0x7fffu + ((u >> 16) & 1u);
    return (unsigned short)(r >> 16);
}
__device__ __forceinline__ float bf2f(unsigned short b) {
    unsigned u = ((unsigned)b) << 16;
    return __builtin_bit_cast(float, u);
}

__device__ __forceinline__ float pw64_sq(const float* v) {
    float r[8];
#pragma unroll
    for (int l = 0; l < 8; ++l) r[l] = v[l] * v[l];
#pragma unroll
    for (int t = 1; t < 8; ++t)
#pragma unroll
        for (int l = 0; l < 8; ++l) r[l] += v[8 * t + l] * v[8 * t + l];
    return ((r[0] + r[1]) + (r[2] + r[3])) + ((r[4] + r[5]) + (r[6] + r[7]));
}

__global__ __launch_bounds__(256) void k_h(const float* __restrict__ cb,
                                           float* __restrict__ h) {
    int j = blockIdx.x * 256 + threadIdx.x;
    if (j < N_E) {
        float e[E_DIM];
        const float4* ep = reinterpret_cast<const float4*>(cb + (size_t)j * E_DIM);
#pragma unroll
        for (int k4 = 0; k4 < E_DIM / 4; ++k4) {
            float4 v = ep[k4];
            e[4 * k4 + 0] = v.x; e[4 * k4 + 1] = v.y;
            e[4 * k4 + 2] = v.z; e[4 * k4 + 3] = v.w;
        }
        h[j] = pw64_sq(e);
    }
}

// Pack codebook into MFMA B-fragment order (bf16 hi/lo split).
// Linear t = ct*1024 + ks*512 + lane*8 + e  <->  B[k][n]: n=lane&15, k=ks*32+(lane>>4)*8+e
__global__ __launch_bounds__(256) void k_prep(const float* __restrict__ cb,
                                              unsigned short* __restrict__ ebh,
                                              unsigned short* __restrict__ ebl) {
    int t = blockIdx.x * 256 + threadIdx.x;
    int e = t & 7, lane = (t >> 3) & 63, ks = (t >> 9) & 1, ct = t >> 10;
    int j = ct * 16 + (lane & 15);
    int k = ks * 32 + ((lane >> 4) << 3) + e;
    float v = cb[j * 64 + k];
    unsigned short hi = f2bf_rn(v);
    ebh[t] = hi;
    ebl[t] = f2bf_rn(v - bf2f(hi));
}

// Block = 4 waves x 64 lanes; wave = one 16-row tile x all 1024 codes.
__global__ __launch_bounds__(256, 4) void k_mfma(
    const float* __restrict__ z, const float* __restrict__ cb,
    const float* __restrict__ h,
    const unsigned short* __restrict__ ebh, const unsigned short* __restrict__ ebl,
    float* __restrict__ out_zq, float* __restrict__ out_idx,
    unsigned* __restrict__ hist, double* __restrict__ sse,
    unsigned* __restrict__ flagN, unsigned* __restrict__ flagL) {
    const int lane = threadIdx.x & 63;
    const int w = __builtin_amdgcn_readfirstlane(threadIdx.x >> 6);
    const int m = lane & 15, g = lane >> 4;

    __shared__ int bok;
    __shared__ float rs[4][16];
    if (threadIdx.x == 0) bok = 1;
    __syncthreads();

    // ---- MFMA layout self-test (asymmetric integer patterns, exact) ----
    {
        bf16x8 a, b;
#pragma unroll
        for (int e = 0; e < 8; ++e) {
            int k = g * 8 + e;
            a[e] = (short)f2bf_rn((float)(((m * 3 + k * 7) & 15) - 7));
            b[e] = (short)f2bf_rn((float)(((k * 5 + m * 3) & 15) - 8));
        }
        f32x4 acc = {0.f, 0.f, 0.f, 0.f};
        acc = MFMA(a, b, acc);
        bool ok = true;
#pragma unroll
        for (int r = 0; r < 4; ++r) {
            int rw = g * 4 + r;
            float E = 0.f;
            for (int k = 0; k < 32; ++k)
                E += (float)((((rw * 3 + k * 7) & 15) - 7) * (((k * 5 + m * 3) & 15) - 8));
            ok = ok && (acc[r] == E);
        }
        if (!ok) atomicAnd(&bok, 0);
    }
    __syncthreads();
    if (!bok) {   // layout assumption wrong: defer whole block to exact cleanup
        if (threadIdx.x < 64) {
            unsigned p = atomicAdd(flagN, 1u);
            flagL[p] = (unsigned)(blockIdx.x * 64 + threadIdx.x);
        }
        return;
    }

    // ---- A-load: z rows, hi/lo split of 2z, and per-row Sum|z| ----
    const int rowb = blockIdx.x * 64 + w * 16;
    const int rowA = rowb + m;
    const float4* zr = reinterpret_cast<const float4*>(z + (size_t)rowA * 64);
    float4 p0 = zr[g * 2], p1 = zr[g * 2 + 1], p2 = zr[8 + g * 2], p3 = zr[9 + g * 2];
    bf16x8 ah0, al0, ah1, al1;
    {
        float t0[8] = {p0.x, p0.y, p0.z, p0.w, p1.x, p1.y, p1.z, p1.w};
        float t1[8] = {p2.x, p2.y, p2.z, p2.w, p3.x, p3.y, p3.z, p3.w};
        float s = 0.f;
#pragma unroll
        for (int e = 0; e < 8; ++e) {
            s += fabsf(t0[e]) + fabsf(t1[e]);
            float a0 = 2.0f * t0[e]; unsigned short h0 = f2bf_rn(a0);
            ah0[e] = (short)h0; al0[e] = (short)f2bf_rn(a0 - bf2f(h0));
            float a1 = 2.0f * t1[e]; unsigned short h1 = f2bf_rn(a1);
            ah1[e] = (short)h1; al1[e] = (short)f2bf_rn(a1 - bf2f(h1));
        }
        s += __shfl_xor(s, 16);
        s += __shfl_xor(s, 32);
        if (g == 0) rs[w][m] = s;
    }

    // ---- scan: 64 col-tiles, best-2 tracking per row-slot ----
    float b00 = INFINITY, b01 = INFINITY, b02 = INFINITY, b03 = INFINITY;
    float b10 = INFINITY, b11 = INFINITY, b12 = INFINITY, b13 = INFINITY;
    int   i00 = 0, i01 = 0, i02 = 0, i03 = 0;
    const bf16x8* pBh = reinterpret_cast<const bf16x8*>(ebh);
    const bf16x8* pBl = reinterpret_cast<const bf16x8*>(ebl);
#pragma unroll 1
    for (int ct = 0; ct < 64; ++ct) {
        const int fb = ct * 128 + lane;
        bf16x8 vbh0 = pBh[fb], vbh1 = pBh[fb + 64];
        bf16x8 vbl0 = pBl[fb], vbl1 = pBl[fb + 64];
        f32x4 acc1 = {0.f, 0.f, 0.f, 0.f}, acc2 = {0.f, 0.f, 0.f, 0.f};
        acc1 = MFMA(ah0, vbh0, acc1);
        acc2 = MFMA(ah1, vbh1, acc2);
        acc1 = MFMA(ah0, vbl0, acc1);
        acc2 = MFMA(ah1, vbl1, acc2);
        acc1 = MFMA(al0, vbh0, acc1);
        acc2 = MFMA(al1, vbh1, acc2);
        const int j = ct * 16 + m;
        const float hj = h[j];
        float s0 = hj - (acc1[0] + acc2[0]);
        float s1 = hj - (acc1[1] + acc2[1]);
        float s2 = hj - (acc1[2] + acc2[2]);
        float s3 = hj - (acc1[3] + acc2[3]);
        if (s0 < b00) { b10 = b00; b00 = s0; i00 = j; } else b10 = fminf(b10, s0);
        if (s1 < b01) { b11 = b01; b01 = s1; i01 = j; } else b11 = fminf(b11, s1);
        if (s2 < b02) { b12 = b02; b02 = s2; i02 = j; } else b12 = fminf(b12, s2);
        if (s3 < b03) { b13 = b03; b03 = s3; i03 = j; } else b13 = fminf(b13, s3);
    }

    // ---- reduce best/2nd across the 16 col-lanes of each group ----
#pragma unroll
    for (int mask = 1; mask < 16; mask <<= 1) {
#define MRG(B0, I0, B1) { float ob0 = __shfl_xor(B0, mask); int oi = __shfl_xor(I0, mask); \
        float ob1 = __shfl_xor(B1, mask); \
        if (ob0 < B0) { B1 = fminf(fminf(B0, B1), ob1); B0 = ob0; I0 = oi; } \
        else { B1 = fminf(B1, fminf(ob0, ob1)); } }
        MRG(b00, i00, b10) MRG(b01, i01, b11) MRG(b02, i02, b12) MRG(b03, i03, b13)
#undef MRG
    }

    // ---- epilogue: 4 lanes per row (r = m>>2, q = m&3) ----
    const int r = m >> 2, q = m & 3;
    float vb0 = (r == 0) ? b00 : (r == 1) ? b01 : (r == 2) ? b02 : b03;
    float vb1 = (r == 0) ? b10 : (r == 1) ? b11 : (r == 2) ? b12 : b13;
    int   vi  = (r == 0) ? i00 : (r == 1) ? i01 : (r == 2) ? i02 : i03;
    const int rloc = g * 4 + r;
    const int rowO = rowb + rloc;
    const float Delta = 6e-8f * rs[w][rloc] + 2.2e-5f;
    float local = 0.f;
    if (vb1 - vb0 <= Delta) {
        if (q == 0) { unsigned p = atomicAdd(flagN, 1u); flagL[p] = (unsigned)rowO; }
    } else {
        if (q == 0) { out_idx[rowO] = (float)vi; atomicAdd(&hist[vi], 1u); }
        const float4* cv = reinterpret_cast<const float4*>(cb + (size_t)vi * 64) + q * 4;
        const float4* zv = reinterpret_cast<const float4*>(z + (size_t)rowO * 64) + q * 4;
        float* orow = out_zq + (size_t)rowO * 64 + q * 16;
#pragma unroll
        for (int u = 0; u < 4; ++u) {
            float4 cc = cv[u], zz = zv[u];
            orow[4 * u + 0] = cc.x; orow[4 * u + 1] = cc.y;
            orow[4 * u + 2] = cc.z; orow[4 * u + 3] = cc.w;
            float dx = cc.x - zz.x, dy = cc.y - zz.y;
            float dz = cc.z - zz.z, dw = cc.w - zz.w;
            local = fmaf(dx, dx, local); local = fmaf(dy, dy, local);
            local = fmaf(dz, dz, local); local = fmaf(dw, dw, local);
        }
    }
#pragma unroll
    for (int off = 32; off; off >>= 1) local += __shfl_down(local, off);
    if (lane == 0) atomicAdd(sse, (double)local);
}

// Exact re-scan for flagged rows: ONE WAVE PER ROW (was 1 thread/row = 403us
// latency disaster). Lane l scans j = l + 64t, t=0..15; per-(row,j) chain is
// bit-identical to the round-3 kernel; cross-lane tie-break on lower j gives
// np.argmin first-occurrence semantics on exact-equal scores.
__global__ __launch_bounds__(64, 4) void k_cleanup(
    const float* __restrict__ z, const float* __restrict__ cb,
    const float* __restrict__ h,
    const unsigned* __restrict__ flagN, const unsigned* __restrict__ flagL,
    float* __restrict__ out_zq, float* __restrict__ out_idx,
    unsigned* __restrict__ hist, double* __restrict__ sse) {
    const unsigned n = *flagN;
    const int lane = threadIdx.x;

    for (unsigned f = blockIdx.x; f < n; f += gridDim.x) {
        const int row = (int)flagL[f];

        // every lane loads the full z row (L1-broadcast), exact round-3 prep
        float tz[E_DIM];
        const float4* zp = reinterpret_cast<const float4*>(z + (size_t)row * 64);
#pragma unroll
        for (int k4 = 0; k4 < 16; ++k4) {
            float4 v = zp[k4];
            tz[4 * k4 + 0] = v.x; tz[4 * k4 + 1] = v.y;
            tz[4 * k4 + 2] = v.z; tz[4 * k4 + 3] = v.w;
        }
        const float nz = pw64_sq(tz);
#pragma unroll
        for (int k = 0; k < 64; ++k) tz[k] = 2.0f * tz[k];

        float bs = INFINITY;
        int bj = 0;
#pragma unroll 2
        for (int t = 0; t < 16; ++t) {
            const int j = lane + 64 * t;           // ascending j per lane
            const float4* cv = reinterpret_cast<const float4*>(cb + (size_t)j * 64);
            float mm = 0.f;
#pragma unroll
            for (int k4 = 0; k4 < 16; ++k4) {      // k ascending: exact chain
                float4 e = cv[k4];
                mm = fmaf(tz[4 * k4 + 0], e.x, mm);
                mm = fmaf(tz[4 * k4 + 1], e.y, mm);
                mm = fmaf(tz[4 * k4 + 2], e.z, mm);
                mm = fmaf(tz[4 * k4 + 3], e.w, mm);
            }
            float s = (nz + h[j]) - mm;
            if (s < bs) { bs = s; bj = j; }        // strict <: lowest j per lane
        }
        // wave reduce: min score, tie -> lower j (== np.argmin first-occurrence)
#pragma unroll
        for (int off = 32; off; off >>= 1) {
            float s2 = __shfl_down(bs, off);
            int   j2 = __shfl_down(bj, off);
            if (s2 < bs || (s2 == bs && j2 < bj)) { bs = s2; bj = j2; }
        }
        bj = __shfl(bj, 0);

        // epilogue: 64 lanes write one z_q element each
        float c = cb[(size_t)bj * 64 + lane];
        out_zq[(size_t)row * 64 + lane] = c;
        float d = c - 0.5f * tz[lane];
        float l2 = d * d;
#pragma unroll
        for (int off = 32; off; off >>= 1) l2 += __shfl_down(l2, off);
        if (lane == 0) {
            out_idx[row] = (float)bj;
            atomicAdd(&hist[bj], 1u);
            atomicAdd(sse, (double)l2);
        }
    }
}

// ---- round-5 fallback scan (used only if ws_size is too small) ----
__global__ __launch_bounds__(512, 2) void k_scan_fb(
    const float* __restrict__ z, const float* __restrict__ cb,
    const float* __restrict__ h,
    float* __restrict__ out_zq, float* __restrict__ out_idx,
    unsigned* __restrict__ hist, double* __restrict__ sse) {
    const int lane = threadIdx.x & 63;
    const int w = __builtin_amdgcn_readfirstlane(threadIdx.x >> 6);
    const int row = blockIdx.x * 64 + lane;
    float tz[E_DIM];
    const float4* zp = reinterpret_cast<const float4*>(z + (size_t)row * E_DIM);
#pragma unroll
    for (int k4 = 0; k4 < E_DIM / 4; ++k4) {
        float4 v = zp[k4];
        tz[4 * k4 + 0] = v.x; tz[4 * k4 + 1] = v.y;
        tz[4 * k4 + 2] = v.z; tz[4 * k4 + 3] = v.w;
    }
    const float nz = pw64_sq(tz);
#pragma unroll
    for (int k = 0; k < E_DIM; ++k) tz[k] = 2.0f * tz[k];
    float b0 = INFINITY; int bi = 0;
    const int j0 = w * 128;
#pragma unroll 1
    for (int j = j0; j < j0 + 128; j += 4) {
        const float* c0 = cb + (size_t)j * E_DIM;
        float m0 = 0.f, m1 = 0.f, m2 = 0.f, m3 = 0.f;
#pragma unroll
        for (int k = 0; k < E_DIM; ++k) {
            float wk = tz[k];
            m0 = fmaf(wk, c0[0 * E_DIM + k], m0);
            m1 = fmaf(wk, c0[1 * E_DIM + k], m1);
            m2 = fmaf(wk, c0[2 * E_DIM + k], m2);
            m3 = fmaf(wk, c0[3 * E_DIM + k], m3);
        }
        float s0 = (nz + h[j + 0]) - m0;
        float s1 = (nz + h[j + 1]) - m1;
        float s2 = (nz + h[j + 2]) - m2;
        float s3 = (nz + h[j + 3]) - m3;
        if (s0 < b0) { b0 = s0; bi = j + 0; }
        if (s1 < b0) { b0 = s1; bi = j + 1; }
        if (s2 < b0) { b0 = s2; bi = j + 2; }
        if (s3 < b0) { b0 = s3; bi = j + 3; }
    }
    __shared__ float lb[8][64];
    __shared__ int   li[8][64];
    lb[w][lane] = b0; li[w][lane] = bi;
    __syncthreads();
    if (threadIdx.x < 64) {
        float b = lb[0][lane]; int i = li[0][lane];
#pragma unroll
        for (int c = 1; c < 8; ++c) {
            float bc = lb[c][lane]; int ic = li[c][lane];
            if (bc < b) { b = bc; i = ic; }
        }
        out_idx[row] = (float)i;
        float local = 0.f;
        const float4* cv = reinterpret_cast<const float4*>(cb + (size_t)i * E_DIM);
        float* orow = out_zq + (size_t)row * E_DIM;
#pragma unroll
        for (int k4 = 0; k4 < E_DIM / 4; ++k4) {
            float4 c = cv[k4];
            float zx = 0.5f * tz[4 * k4 + 0], zy = 0.5f * tz[4 * k4 + 1];
            float zz = 0.5f * tz[4 * k4 + 2], zw = 0.5f * tz[4 * k4 + 3];
            orow[4 * k4 + 0] = c.x; orow[4 * k4 + 1] = c.y;
            orow[4 * k4 + 2] = c.z; orow[4 * k4 + 3] = c.w;
            float dx = c.x - zx, dy = c.y - zy, dz = c.z - zz, dw = c.w - zw;
            local = fmaf(dx, dx, local); local = fmaf(dy, dy, local);
            local = fmaf(dz, dz, local); local = fmaf(dw, dw, local);
        }
        atomicAdd(&hist[i], 1u);
#pragma unroll
        for (int off = 32; off; off >>= 1) local += __shfl_down(local, off);
        if (lane == 0) atomicAdd(sse, (double)local);
    }
}

__global__ __launch_bounds__(256) void k_final(
    const unsigned* __restrict__ hist, const double* __restrict__ sse,
    float* __restrict__ out, int nrows) {
    __shared__ double sh[256];
    double acc = 0.0;
    for (int j = threadIdx.x; j < N_E; j += 256) {
        double p = (double)hist[j] / (double)nrows;
        acc += p * log(p + 1e-10);
    }
    sh[threadIdx.x] = acc;
    __syncthreads();
    for (int s = 128; s; s >>= 1) {
        if (threadIdx.x < s) sh[threadIdx.x] += sh[threadIdx.x + s];
        __syncthreads();
    }
    if (threadIdx.x == 0) {
        double ntot = (double)nrows * (double)E_DIM;
        out[0] = (float)((1.0 + BETA) * (*sse) / ntot);               // loss
        out[1 + (size_t)nrows * E_DIM] = (float)exp(-sh[0]);          // perplexity
    }
}

extern "C" void kernel_launch(void* const* d_in, const int* in_sizes, int n_in,
                              void* d_out, int out_size, void* d_ws, size_t ws_size,
                              hipStream_t stream) {
    const float* z  = (const float*)d_in[0];
    const float* cb = (const float*)d_in[1];
    const int nrows = in_sizes[0] / E_DIM;   // 65536
    float* out = (float*)d_out;

    char* ws = (char*)d_ws;
    unsigned* hist  = (unsigned*)(ws + 0);
    double*   sse   = (double*)  (ws + 4096);
    unsigned* flagN = (unsigned*)(ws + 4104);
    float*    h     = (float*)   (ws + 4112);
    unsigned short* ebh = (unsigned short*)(ws + 8208);
    unsigned short* ebl = (unsigned short*)(ws + 139280);
    unsigned* flagL = (unsigned*)(ws + 270352);
    // end of ws use: 270352 + 262144 = 532496 bytes

    float* out_zq  = out + 1;
    float* out_idx = out + 1 + (size_t)nrows * E_DIM + 1;

    hipMemsetAsync(d_ws, 0, 4112, stream);  // hist + sse + flagN
    k_h<<<(N_E + 255) / 256, 256, 0, stream>>>(cb, h);

    if (ws_size >= 532496) {
        k_prep<<<256, 256, 0, stream>>>(cb, ebh, ebl);
        k_mfma<<<nrows / 64, 256, 0, stream>>>(z, cb, h, ebh, ebl,
                                               out_zq, out_idx, hist, sse, flagN, flagL);
        k_cleanup<<<2048, 64, 0, stream>>>(z, cb, h, flagN, flagL,
                                           out_zq, out_idx, hist, sse);
    } else {
        k_scan_fb<<<nrows / 64, 512, 0, stream>>>(z, cb, h, out_zq, out_idx, hist, sse);
    }
    k_final<<<1, 256, 0, stream>>>(hist, sse, out, nrows);
}

// Round 10
// 145.072 us; speedup vs baseline: 2.8120x; 1.0333x over previous
//
#include <hip/hip_runtime.h>
#include <math.h>

#define E_DIM 64
#define N_E   1024
#define BETA  0.25

using bf16x8 = __attribute__((ext_vector_type(8))) short;
using f32x4  = __attribute__((ext_vector_type(4))) float;
#define MFMA(a, b, c) __builtin_amdgcn_mfma_f32_16x16x32_bf16((a), (b), (c), 0, 0, 0)

// global -> LDS direct copy, 16B per lane; LDS dest = uniform base + lane*16
#define GLOAD_LDS(g, l) __builtin_amdgcn_global_load_lds(                      \
    (const __attribute__((address_space(1))) void*)(g),                        \
    (__attribute__((address_space(3))) void*)(l), 16, 0, 0)

// ---------------------------------------------------------------------------
// Numerics contract (idx must match the fp32 numpy reference exactly):
//   exact score_j = h_j - m_ij, m = sequential fp32 FMA chain (round-3 proven)
//   MFMA path: s~_j = h_j - [2z]_hi/lo x [e]_hi/lo (3 bf16 MFMA terms, fp32 acc)
//   Rows with (2nd-best - best) <= Delta_row are flagged and re-resolved with
//   the exact round-3 chain by k_cleanup (one wave/row, tie -> lower j).
// Round-10 change: B-fragments staged global->LDS per BLOCK (8 chunks,
// double-buffered, global_load_lds) instead of streamed per wave. Data path
// only — fragment values and MFMA sequence unchanged.
//
// ws: [0,4096) hist | [4096] sse f64 | [4104] flagN u32 | [4112,8208) h f32
//     [8208) ebh bf16[65536] | [139280) ebl | [270352) flagL u32[65536]
// ---------------------------------------------------------------------------

__device__ __forceinline__ unsigned short f2bf_rn(float f) {
    unsigned u = __builtin_bit_cast(unsigned, f);
    unsigned r = u + 0x7fffu + ((u >> 16) & 1u);
    return (unsigned short)(r >> 16);
}
__device__ __forceinline__ float bf2f(unsigned short b) {
    unsigned u = ((unsigned)b) << 16;
    return __builtin_bit_cast(float, u);
}

__device__ __forceinline__ float pw64_sq(const float* v) {
    float r[8];
#pragma unroll
    for (int l = 0; l < 8; ++l) r[l] = v[l] * v[l];
#pragma unroll
    for (int t = 1; t < 8; ++t)
#pragma unroll
        for (int l = 0; l < 8; ++l) r[l] += v[8 * t + l] * v[8 * t + l];
    return ((r[0] + r[1]) + (r[2] + r[3])) + ((r[4] + r[5]) + (r[6] + r[7]));
}

__global__ __launch_bounds__(256) void k_h(const float* __restrict__ cb,
                                           float* __restrict__ h) {
    int j = blockIdx.x * 256 + threadIdx.x;
    if (j < N_E) {
        float e[E_DIM];
        const float4* ep = reinterpret_cast<const float4*>(cb + (size_t)j * E_DIM);
#pragma unroll
        for (int k4 = 0; k4 < E_DIM / 4; ++k4) {
            float4 v = ep[k4];
            e[4 * k4 + 0] = v.x; e[4 * k4 + 1] = v.y;
            e[4 * k4 + 2] = v.z; e[4 * k4 + 3] = v.w;
        }
        h[j] = pw64_sq(e);
    }
}

// Pack codebook into MFMA B-fragment order (bf16 hi/lo split).
// Linear t = ct*1024 + ks*512 + lane*8 + e  <->  B[k][n]: n=lane&15, k=ks*32+(lane>>4)*8+e
__global__ __launch_bounds__(256) void k_prep(const float* __restrict__ cb,
                                              unsigned short* __restrict__ ebh,
                                              unsigned short* __restrict__ ebl) {
    int t = blockIdx.x * 256 + threadIdx.x;
    int e = t & 7, lane = (t >> 3) & 63, ks = (t >> 9) & 1, ct = t >> 10;
    int j = ct * 16 + (lane & 15);
    int k = ks * 32 + ((lane >> 4) << 3) + e;
    float v = cb[j * 64 + k];
    unsigned short hi = f2bf_rn(v);
    ebh[t] = hi;
    ebl[t] = f2bf_rn(v - bf2f(hi));
}

// Block = 4 waves x 64 lanes; wave = one 16-row tile x all 1024 codes.
// B-fragments staged to LDS per block: 8 chunks x (16KB hi + 16KB lo), dbuf.
__global__ __launch_bounds__(256, 2) void k_mfma(
    const float* __restrict__ z, const float* __restrict__ cb,
    const float* __restrict__ h,
    const unsigned short* __restrict__ ebh, const unsigned short* __restrict__ ebl,
    float* __restrict__ out_zq, float* __restrict__ out_idx,
    unsigned* __restrict__ hist, double* __restrict__ sse,
    unsigned* __restrict__ flagN, unsigned* __restrict__ flagL) {
    const int lane = threadIdx.x & 63;
    const int w = __builtin_amdgcn_readfirstlane(threadIdx.x >> 6);
    const int m = lane & 15, g = lane >> 4;

    __shared__ __align__(16) unsigned char sB[2][2][16384];  // [buf][hi/lo][bytes]
    __shared__ int bok;
    __shared__ float rs[4][16];
    if (threadIdx.x == 0) bok = 1;
    __syncthreads();

    // ---- MFMA layout self-test (asymmetric integer patterns, exact) ----
    {
        bf16x8 a, b;
#pragma unroll
        for (int e = 0; e < 8; ++e) {
            int k = g * 8 + e;
            a[e] = (short)f2bf_rn((float)(((m * 3 + k * 7) & 15) - 7));
            b[e] = (short)f2bf_rn((float)(((k * 5 + m * 3) & 15) - 8));
        }
        f32x4 acc = {0.f, 0.f, 0.f, 0.f};
        acc = MFMA(a, b, acc);
        bool ok = true;
#pragma unroll
        for (int r = 0; r < 4; ++r) {
            int rw = g * 4 + r;
            float E = 0.f;
            for (int k = 0; k < 32; ++k)
                E += (float)((((rw * 3 + k * 7) & 15) - 7) * (((k * 5 + m * 3) & 15) - 8));
            ok = ok && (acc[r] == E);
        }
        if (!ok) atomicAnd(&bok, 0);
    }
    __syncthreads();
    if (!bok) {   // layout assumption wrong: defer whole block to exact cleanup
        if (threadIdx.x < 64) {
            unsigned p = atomicAdd(flagN, 1u);
            flagL[p] = (unsigned)(blockIdx.x * 64 + threadIdx.x);
        }
        return;
    }

    // ---- A-load: z rows, hi/lo split of 2z, and per-row Sum|z| ----
    const int rowb = blockIdx.x * 64 + w * 16;
    const int rowA = rowb + m;
    const float4* zr = reinterpret_cast<const float4*>(z + (size_t)rowA * 64);
    float4 p0 = zr[g * 2], p1 = zr[g * 2 + 1], p2 = zr[8 + g * 2], p3 = zr[9 + g * 2];
    bf16x8 ah0, al0, ah1, al1;
    {
        float t0[8] = {p0.x, p0.y, p0.z, p0.w, p1.x, p1.y, p1.z, p1.w};
        float t1[8] = {p2.x, p2.y, p2.z, p2.w, p3.x, p3.y, p3.z, p3.w};
        float s = 0.f;
#pragma unroll
        for (int e = 0; e < 8; ++e) {
            s += fabsf(t0[e]) + fabsf(t1[e]);
            float a0 = 2.0f * t0[e]; unsigned short h0 = f2bf_rn(a0);
            ah0[e] = (short)h0; al0[e] = (short)f2bf_rn(a0 - bf2f(h0));
            float a1 = 2.0f * t1[e]; unsigned short h1 = f2bf_rn(a1);
            ah1[e] = (short)h1; al1[e] = (short)f2bf_rn(a1 - bf2f(h1));
        }
        s += __shfl_xor(s, 16);
        s += __shfl_xor(s, 32);
        if (g == 0) rs[w][m] = s;
    }

    // ---- staging: chunk c = cts [8c, 8c+8) = 16KB of ebh + 16KB of ebl ----
#define STAGE(c, buf) {                                                        \
        const unsigned char* gh = (const unsigned char*)ebh +                  \
            (size_t)(c) * 16384 + w * 4096 + lane * 16;                        \
        const unsigned char* gl = (const unsigned char*)ebl +                  \
            (size_t)(c) * 16384 + w * 4096 + lane * 16;                        \
        unsigned char* dh = &sB[buf][0][w * 4096];                             \
        unsigned char* dl = &sB[buf][1][w * 4096];                             \
        _Pragma("unroll")                                                      \
        for (int u = 0; u < 4; ++u) {                                          \
            GLOAD_LDS(gh + u * 1024, dh + u * 1024);                           \
            GLOAD_LDS(gl + u * 1024, dl + u * 1024);                           \
        }                                                                      \
    }

    // ---- scan: 8 chunks x 8 col-tiles, best-2 tracking per row-slot ----
    float b00 = INFINITY, b01 = INFINITY, b02 = INFINITY, b03 = INFINITY;
    float b10 = INFINITY, b11 = INFINITY, b12 = INFINITY, b13 = INFINITY;
    int   i00 = 0, i01 = 0, i02 = 0, i03 = 0;

    STAGE(0, 0);
    __syncthreads();   // vmcnt drain: chunk 0 visible to all waves
#pragma unroll 1
    for (int c = 0; c < 8; ++c) {
        if (c + 1 < 8) STAGE(c + 1, (c + 1) & 1);   // issue-early, overlaps compute
        const bf16x8* sBh = reinterpret_cast<const bf16x8*>(&sB[c & 1][0][0]);
        const bf16x8* sBl = reinterpret_cast<const bf16x8*>(&sB[c & 1][1][0]);
#pragma unroll
        for (int ct8 = 0; ct8 < 8; ++ct8) {
            const int fb = ct8 * 128 + lane;
            bf16x8 vbh0 = sBh[fb], vbh1 = sBh[fb + 64];
            bf16x8 vbl0 = sBl[fb], vbl1 = sBl[fb + 64];
            f32x4 acc1 = {0.f, 0.f, 0.f, 0.f}, acc2 = {0.f, 0.f, 0.f, 0.f};
            acc1 = MFMA(ah0, vbh0, acc1);
            acc2 = MFMA(ah1, vbh1, acc2);
            acc1 = MFMA(ah0, vbl0, acc1);
            acc2 = MFMA(ah1, vbl1, acc2);
            acc1 = MFMA(al0, vbh0, acc1);
            acc2 = MFMA(al1, vbh1, acc2);
            const int j = (c * 8 + ct8) * 16 + m;
            const float hj = h[j];
            float s0 = hj - (acc1[0] + acc2[0]);
            float s1 = hj - (acc1[1] + acc2[1]);
            float s2 = hj - (acc1[2] + acc2[2]);
            float s3 = hj - (acc1[3] + acc2[3]);
            if (s0 < b00) { b10 = b00; b00 = s0; i00 = j; } else b10 = fminf(b10, s0);
            if (s1 < b01) { b11 = b01; b01 = s1; i01 = j; } else b11 = fminf(b11, s1);
            if (s2 < b02) { b12 = b02; b02 = s2; i02 = j; } else b12 = fminf(b12, s2);
            if (s3 < b03) { b13 = b03; b03 = s3; i03 = j; } else b13 = fminf(b13, s3);
        }
        __syncthreads();   // staged chunk c+1 visible; buf (c&1) free for reuse
    }
#undef STAGE

    // ---- reduce best/2nd across the 16 col-lanes of each group ----
#pragma unroll
    for (int mask = 1; mask < 16; mask <<= 1) {
#define MRG(B0, I0, B1) { float ob0 = __shfl_xor(B0, mask); int oi = __shfl_xor(I0, mask); \
        float ob1 = __shfl_xor(B1, mask); \
        if (ob0 < B0) { B1 = fminf(fminf(B0, B1), ob1); B0 = ob0; I0 = oi; } \
        else { B1 = fminf(B1, fminf(ob0, ob1)); } }
        MRG(b00, i00, b10) MRG(b01, i01, b11) MRG(b02, i02, b12) MRG(b03, i03, b13)
#undef MRG
    }

    // ---- epilogue: 4 lanes per row (r = m>>2, q = m&3) ----
    const int r = m >> 2, q = m & 3;
    float vb0 = (r == 0) ? b00 : (r == 1) ? b01 : (r == 2) ? b02 : b03;
    float vb1 = (r == 0) ? b10 : (r == 1) ? b11 : (r == 2) ? b12 : b13;
    int   vi  = (r == 0) ? i00 : (r == 1) ? i01 : (r == 2) ? i02 : i03;
    const int rloc = g * 4 + r;
    const int rowO = rowb + rloc;
    const float Delta = 6e-8f * rs[w][rloc] + 2.2e-5f;
    float local = 0.f;
    if (vb1 - vb0 <= Delta) {
        if (q == 0) { unsigned p = atomicAdd(flagN, 1u); flagL[p] = (unsigned)rowO; }
    } else {
        if (q == 0) { out_idx[rowO] = (float)vi; atomicAdd(&hist[vi], 1u); }
        const float4* cv = reinterpret_cast<const float4*>(cb + (size_t)vi * 64) + q * 4;
        const float4* zv = reinterpret_cast<const float4*>(z + (size_t)rowO * 64) + q * 4;
        float* orow = out_zq + (size_t)rowO * 64 + q * 16;
#pragma unroll
        for (int u = 0; u < 4; ++u) {
            float4 cc = cv[u], zz = zv[u];
            orow[4 * u + 0] = cc.x; orow[4 * u + 1] = cc.y;
            orow[4 * u + 2] = cc.z; orow[4 * u + 3] = cc.w;
            float dx = cc.x - zz.x, dy = cc.y - zz.y;
            float dz = cc.z - zz.z, dw = cc.w - zz.w;
            local = fmaf(dx, dx, local); local = fmaf(dy, dy, local);
            local = fmaf(dz, dz, local); local = fmaf(dw, dw, local);
        }
    }
#pragma unroll
    for (int off = 32; off; off >>= 1) local += __shfl_down(local, off);
    if (lane == 0) atomicAdd(sse, (double)local);
}

// Exact re-scan for flagged rows: one wave per row, 16 codes per lane.
__global__ __launch_bounds__(64, 4) void k_cleanup(
    const float* __restrict__ z, const float* __restrict__ cb,
    const float* __restrict__ h,
    const unsigned* __restrict__ flagN, const unsigned* __restrict__ flagL,
    float* __restrict__ out_zq, float* __restrict__ out_idx,
    unsigned* __restrict__ hist, double* __restrict__ sse) {
    const unsigned n = *flagN;
    const int lane = threadIdx.x;

    for (unsigned f = blockIdx.x; f < n; f += gridDim.x) {
        const int row = (int)flagL[f];

        float tz[E_DIM];
        const float4* zp = reinterpret_cast<const float4*>(z + (size_t)row * 64);
#pragma unroll
        for (int k4 = 0; k4 < 16; ++k4) {
            float4 v = zp[k4];
            tz[4 * k4 + 0] = v.x; tz[4 * k4 + 1] = v.y;
            tz[4 * k4 + 2] = v.z; tz[4 * k4 + 3] = v.w;
        }
        const float nz = pw64_sq(tz);
#pragma unroll
        for (int k = 0; k < 64; ++k) tz[k] = 2.0f * tz[k];

        float bs = INFINITY;
        int bj = 0;
#pragma unroll 2
        for (int t = 0; t < 16; ++t) {
            const int j = lane + 64 * t;           // ascending j per lane
            const float4* cv = reinterpret_cast<const float4*>(cb + (size_t)j * 64);
            float mm = 0.f;
#pragma unroll
            for (int k4 = 0; k4 < 16; ++k4) {      // k ascending: exact chain
                float4 e = cv[k4];
                mm = fmaf(tz[4 * k4 + 0], e.x, mm);
                mm = fmaf(tz[4 * k4 + 1], e.y, mm);
                mm = fmaf(tz[4 * k4 + 2], e.z, mm);
                mm = fmaf(tz[4 * k4 + 3], e.w, mm);
            }
            float s = (nz + h[j]) - mm;
            if (s < bs) { bs = s; bj = j; }        // strict <: lowest j per lane
        }
#pragma unroll
        for (int off = 32; off; off >>= 1) {
            float s2 = __shfl_down(bs, off);
            int   j2 = __shfl_down(bj, off);
            if (s2 < bs || (s2 == bs && j2 < bj)) { bs = s2; bj = j2; }
        }
        bj = __shfl(bj, 0);

        float c = cb[(size_t)bj * 64 + lane];
        out_zq[(size_t)row * 64 + lane] = c;
        float d = c - 0.5f * tz[lane];
        float l2 = d * d;
#pragma unroll
        for (int off = 32; off; off >>= 1) l2 += __shfl_down(l2, off);
        if (lane == 0) {
            out_idx[row] = (float)bj;
            atomicAdd(&hist[bj], 1u);
            atomicAdd(sse, (double)l2);
        }
    }
}

// ---- round-5 fallback scan (used only if ws_size is too small) ----
__global__ __launch_bounds__(512, 2) void k_scan_fb(
    const float* __restrict__ z, const float* __restrict__ cb,
    const float* __restrict__ h,
    float* __restrict__ out_zq, float* __restrict__ out_idx,
    unsigned* __restrict__ hist, double* __restrict__ sse) {
    const int lane = threadIdx.x & 63;
    const int w = __builtin_amdgcn_readfirstlane(threadIdx.x >> 6);
    const int row = blockIdx.x * 64 + lane;
    float tz[E_DIM];
    const float4* zp = reinterpret_cast<const float4*>(z + (size_t)row * E_DIM);
#pragma unroll
    for (int k4 = 0; k4 < E_DIM / 4; ++k4) {
        float4 v = zp[k4];
        tz[4 * k4 + 0] = v.x; tz[4 * k4 + 1] = v.y;
        tz[4 * k4 + 2] = v.z; tz[4 * k4 + 3] = v.w;
    }
    const float nz = pw64_sq(tz);
#pragma unroll
    for (int k = 0; k < E_DIM; ++k) tz[k] = 2.0f * tz[k];
    float b0 = INFINITY; int bi = 0;
    const int j0 = w * 128;
#pragma unroll 1
    for (int j = j0; j < j0 + 128; j += 4) {
        const float* c0 = cb + (size_t)j * E_DIM;
        float m0 = 0.f, m1 = 0.f, m2 = 0.f, m3 = 0.f;
#pragma unroll
        for (int k = 0; k < E_DIM; ++k) {
            float wk = tz[k];
            m0 = fmaf(wk, c0[0 * E_DIM + k], m0);
            m1 = fmaf(wk, c0[1 * E_DIM + k], m1);
            m2 = fmaf(wk, c0[2 * E_DIM + k], m2);
            m3 = fmaf(wk, c0[3 * E_DIM + k], m3);
        }
        float s0 = (nz + h[j + 0]) - m0;
        float s1 = (nz + h[j + 1]) - m1;
        float s2 = (nz + h[j + 2]) - m2;
        float s3 = (nz + h[j + 3]) - m3;
        if (s0 < b0) { b0 = s0; bi = j + 0; }
        if (s1 < b0) { b0 = s1; bi = j + 1; }
        if (s2 < b0) { b0 = s2; bi = j + 2; }
        if (s3 < b0) { b0 = s3; bi = j + 3; }
    }
    __shared__ float lb[8][64];
    __shared__ int   li[8][64];
    lb[w][lane] = b0; li[w][lane] = bi;
    __syncthreads();
    if (threadIdx.x < 64) {
        float b = lb[0][lane]; int i = li[0][lane];
#pragma unroll
        for (int c = 1; c < 8; ++c) {
            float bc = lb[c][lane]; int ic = li[c][lane];
            if (bc < b) { b = bc; i = ic; }
        }
        out_idx[row] = (float)i;
        float local = 0.f;
        const float4* cv = reinterpret_cast<const float4*>(cb + (size_t)i * E_DIM);
        float* orow = out_zq + (size_t)row * E_DIM;
#pragma unroll
        for (int k4 = 0; k4 < E_DIM / 4; ++k4) {
            float4 c = cv[k4];
            float zx = 0.5f * tz[4 * k4 + 0], zy = 0.5f * tz[4 * k4 + 1];
            float zz = 0.5f * tz[4 * k4 + 2], zw = 0.5f * tz[4 * k4 + 3];
            orow[4 * k4 + 0] = c.x; orow[4 * k4 + 1] = c.y;
            orow[4 * k4 + 2] = c.z; orow[4 * k4 + 3] = c.w;
            float dx = c.x - zx, dy = c.y - zy, dz = c.z - zz, dw = c.w - zw;
            local = fmaf(dx, dx, local); local = fmaf(dy, dy, local);
            local = fmaf(dz, dz, local); local = fmaf(dw, dw, local);
        }
        atomicAdd(&hist[i], 1u);
#pragma unroll
        for (int off = 32; off; off >>= 1) local += __shfl_down(local, off);
        if (lane == 0) atomicAdd(sse, (double)local);
    }
}

__global__ __launch_bounds__(256) void k_final(
    const unsigned* __restrict__ hist, const double* __restrict__ sse,
    float* __restrict__ out, int nrows) {
    __shared__ double sh[256];
    double acc = 0.0;
    for (int j = threadIdx.x; j < N_E; j += 256) {
        double p = (double)hist[j] / (double)nrows;
        acc += p * log(p + 1e-10);
    }
    sh[threadIdx.x] = acc;
    __syncthreads();
    for (int s = 128; s; s >>= 1) {
        if (threadIdx.x < s) sh[threadIdx.x] += sh[threadIdx.x + s];
        __syncthreads();
    }
    if (threadIdx.x == 0) {
        double ntot = (double)nrows * (double)E_DIM;
        out[0] = (float)((1.0 + BETA) * (*sse) / ntot);               // loss
        out[1 + (size_t)nrows * E_DIM] = (float)exp(-sh[0]);          // perplexity
    }
}

extern "C" void kernel_launch(void* const* d_in, const int* in_sizes, int n_in,
                              void* d_out, int out_size, void* d_ws, size_t ws_size,
                              hipStream_t stream) {
    const float* z  = (const float*)d_in[0];
    const float* cb = (const float*)d_in[1];
    const int nrows = in_sizes[0] / E_DIM;   // 65536
    float* out = (float*)d_out;

    char* ws = (char*)d_ws;
    unsigned* hist  = (unsigned*)(ws + 0);
    double*   sse   = (double*)  (ws + 4096);
    unsigned* flagN = (unsigned*)(ws + 4104);
    float*    h     = (float*)   (ws + 4112);
    unsigned short* ebh = (unsigned short*)(ws + 8208);
    unsigned short* ebl = (unsigned short*)(ws + 139280);
    unsigned* flagL = (unsigned*)(ws + 270352);
    // end of ws use: 270352 + 262144 = 532496 bytes

    float* out_zq  = out + 1;
    float* out_idx = out + 1 + (size_t)nrows * E_DIM + 1;

    hipMemsetAsync(d_ws, 0, 4112, stream);  // hist + sse + flagN
    k_h<<<(N_E + 255) / 256, 256, 0, stream>>>(cb, h);

    if (ws_size >= 532496) {
        k_prep<<<256, 256, 0, stream>>>(cb, ebh, ebl);
        k_mfma<<<nrows / 64, 256, 0, stream>>>(z, cb, h, ebh, ebl,
                                               out_zq, out_idx, hist, sse, flagN, flagL);
        k_cleanup<<<2048, 64, 0, stream>>>(z, cb, h, flagN, flagL,
                                           out_zq, out_idx, hist, sse);
    } else {
        k_scan_fb<<<nrows / 64, 512, 0, stream>>>(z, cb, h, out_zq, out_idx, hist, sse);
    }
    k_final<<<1, 256, 0, stream>>>(hist, sse, out, nrows);
}

// Round 11
// 121.679 us; speedup vs baseline: 3.3525x; 1.1922x over previous
//
#include <hip/hip_runtime.h>
#include <math.h>

#define E_DIM 64
#define N_E   1024
#define BETA  0.25

using bf16x8 = __attribute__((ext_vector_type(8))) short;
using f32x4  = __attribute__((ext_vector_type(4))) float;
#define MFMA(a, b, c) __builtin_amdgcn_mfma_f32_16x16x32_bf16((a), (b), (c), 0, 0, 0)

// global -> LDS direct copy, 16B per lane; LDS dest = uniform base + lane*16
#define GLOAD_LDS(g, l) __builtin_amdgcn_global_load_lds(                      \
    (const __attribute__((address_space(1))) void*)(g),                        \
    (__attribute__((address_space(3))) void*)(l), 16, 0, 0)

// ---------------------------------------------------------------------------
// Numerics contract (idx must match the fp32 numpy reference exactly):
//   exact score_j = h_j - m_ij, m = sequential fp32 FMA chain (round-3 proven)
//   MFMA path: s~_j = h_j - [2z]_hi/lo x [e]_hi/lo (3 bf16 MFMA terms, fp32
//   acc; terms now in INDEPENDENT accumulators summed at readback — reorder
//   noise << 1e-7, inside Delta slack). Rows with (2nd - best) <= Delta are
//   flagged -> exact round-3 re-scan in k_cleanup (wave/row, tie -> lower j).
//   Exact ties in the approx scores give gap 0 -> always flagged.
// Round-11: 2 A-tiles (32 rows) per wave ->每 B-fragment feeds 12 independent
// MFMAs; LDS read traffic halves; dependency chains gone.
//
// ws: [0,4096) hist | [4096] sse f64 | [4104] flagN u32 | [4112,8208) h f32
//     [8208) ebh bf16[65536] | [139280) ebl | [270352) flagL u32[65536]
// ---------------------------------------------------------------------------

__device__ __forceinline__ unsigned short f2bf_rn(float f) {
    unsigned u = __builtin_bit_cast(unsigned, f);
    unsigned r = u + 0x7fffu + ((u >> 16) & 1u);
    return (unsigned short)(r >> 16);
}
__device__ __forceinline__ float bf2f(unsigned short b) {
    unsigned u = ((unsigned)b) << 16;
    return __builtin_bit_cast(float, u);
}

__device__ __forceinline__ float pw64_sq(const float* v) {
    float r[8];
#pragma unroll
    for (int l = 0; l < 8; ++l) r[l] = v[l] * v[l];
#pragma unroll
    for (int t = 1; t < 8; ++t)
#pragma unroll
        for (int l = 0; l < 8; ++l) r[l] += v[8 * t + l] * v[8 * t + l];
    return ((r[0] + r[1]) + (r[2] + r[3])) + ((r[4] + r[5]) + (r[6] + r[7]));
}

__global__ __launch_bounds__(256) void k_h(const float* __restrict__ cb,
                                           float* __restrict__ h) {
    int j = blockIdx.x * 256 + threadIdx.x;
    if (j < N_E) {
        float e[E_DIM];
        const float4* ep = reinterpret_cast<const float4*>(cb + (size_t)j * E_DIM);
#pragma unroll
        for (int k4 = 0; k4 < E_DIM / 4; ++k4) {
            float4 v = ep[k4];
            e[4 * k4 + 0] = v.x; e[4 * k4 + 1] = v.y;
            e[4 * k4 + 2] = v.z; e[4 * k4 + 3] = v.w;
        }
        h[j] = pw64_sq(e);
    }
}

// Pack codebook into MFMA B-fragment order (bf16 hi/lo split).
__global__ __launch_bounds__(256) void k_prep(const float* __restrict__ cb,
                                              unsigned short* __restrict__ ebh,
                                              unsigned short* __restrict__ ebl) {
    int t = blockIdx.x * 256 + threadIdx.x;
    int e = t & 7, lane = (t >> 3) & 63, ks = (t >> 9) & 1, ct = t >> 10;
    int j = ct * 16 + (lane & 15);
    int k = ks * 32 + ((lane >> 4) << 3) + e;
    float v = cb[j * 64 + k];
    unsigned short hi = f2bf_rn(v);
    ebh[t] = hi;
    ebl[t] = f2bf_rn(v - bf2f(hi));
}

// Block = 4 waves x 64 lanes; wave = TWO 16-row A-tiles (32 rows) x all codes.
__global__ __launch_bounds__(256, 2) void k_mfma(
    const float* __restrict__ z, const float* __restrict__ cb,
    const float* __restrict__ h,
    const unsigned short* __restrict__ ebh, const unsigned short* __restrict__ ebl,
    float* __restrict__ out_zq, float* __restrict__ out_idx,
    unsigned* __restrict__ hist, double* __restrict__ sse,
    unsigned* __restrict__ flagN, unsigned* __restrict__ flagL) {
    const int lane = threadIdx.x & 63;
    const int w = __builtin_amdgcn_readfirstlane(threadIdx.x >> 6);
    const int m = lane & 15, g = lane >> 4;

    __shared__ __align__(16) unsigned char sB[2][2][16384];  // [buf][hi/lo]
    __shared__ int bok;
    __shared__ float rsv[4][32];
    __shared__ float sb0[4][32], sb1[4][32];
    __shared__ int   sbi[4][32];
    if (threadIdx.x == 0) bok = 1;
    __syncthreads();

    // ---- MFMA layout self-test (asymmetric integer patterns, exact) ----
    {
        bf16x8 a, b;
#pragma unroll
        for (int e = 0; e < 8; ++e) {
            int k = g * 8 + e;
            a[e] = (short)f2bf_rn((float)(((m * 3 + k * 7) & 15) - 7));
            b[e] = (short)f2bf_rn((float)(((k * 5 + m * 3) & 15) - 8));
        }
        f32x4 acc = {0.f, 0.f, 0.f, 0.f};
        acc = MFMA(a, b, acc);
        bool ok = true;
#pragma unroll
        for (int r = 0; r < 4; ++r) {
            int rw = g * 4 + r;
            float E = 0.f;
            for (int k = 0; k < 32; ++k)
                E += (float)((((rw * 3 + k * 7) & 15) - 7) * (((k * 5 + m * 3) & 15) - 8));
            ok = ok && (acc[r] == E);
        }
        if (!ok) atomicAnd(&bok, 0);
    }
    __syncthreads();
    if (!bok) {   // layout assumption wrong: defer whole block to exact cleanup
        if (threadIdx.x < 128) {
            unsigned p = atomicAdd(flagN, 1u);
            flagL[p] = (unsigned)(blockIdx.x * 128 + threadIdx.x);
        }
        return;
    }

    // ---- A-load: 2 tiles of z rows, hi/lo split of 2z, per-row Sum|z| ----
    const int rowb32 = blockIdx.x * 128 + w * 32;
    bf16x8 a0h0, a0l0, a0h1, a0l1, a1h0, a1l0, a1h1, a1l1;
#define ALOAD(P, AH0, AL0, AH1, AL1) {                                         \
        const int rowA = rowb32 + (P) * 16 + m;                                \
        const float4* zr = reinterpret_cast<const float4*>(z + (size_t)rowA * 64); \
        float4 p0 = zr[g * 2], p1 = zr[g * 2 + 1];                             \
        float4 p2 = zr[8 + g * 2], p3 = zr[9 + g * 2];                         \
        float t0[8] = {p0.x, p0.y, p0.z, p0.w, p1.x, p1.y, p1.z, p1.w};        \
        float t1[8] = {p2.x, p2.y, p2.z, p2.w, p3.x, p3.y, p3.z, p3.w};        \
        float s = 0.f;                                                         \
        _Pragma("unroll")                                                      \
        for (int e = 0; e < 8; ++e) {                                          \
            s += fabsf(t0[e]) + fabsf(t1[e]);                                  \
            float x0 = 2.0f * t0[e]; unsigned short h0 = f2bf_rn(x0);          \
            AH0[e] = (short)h0; AL0[e] = (short)f2bf_rn(x0 - bf2f(h0));        \
            float x1 = 2.0f * t1[e]; unsigned short h1 = f2bf_rn(x1);          \
            AH1[e] = (short)h1; AL1[e] = (short)f2bf_rn(x1 - bf2f(h1));        \
        }                                                                      \
        s += __shfl_xor(s, 16);                                                \
        s += __shfl_xor(s, 32);                                                \
        if (g == 0) rsv[w][(P) * 16 + m] = s;                                  \
    }
    ALOAD(0, a0h0, a0l0, a0h1, a0l1)
    ALOAD(1, a1h0, a1l0, a1h1, a1l1)
#undef ALOAD

    // ---- staging: chunk c = 16KB of ebh + 16KB of ebl (as round 10) ----
#define STAGE(c, buf) {                                                        \
        const unsigned char* gh = (const unsigned char*)ebh +                  \
            (size_t)(c) * 16384 + w * 4096 + lane * 16;                        \
        const unsigned char* gl = (const unsigned char*)ebl +                  \
            (size_t)(c) * 16384 + w * 4096 + lane * 16;                        \
        unsigned char* dh = &sB[buf][0][w * 4096];                             \
        unsigned char* dl = &sB[buf][1][w * 4096];                             \
        _Pragma("unroll")                                                      \
        for (int u = 0; u < 4; ++u) {                                          \
            GLOAD_LDS(gh + u * 1024, dh + u * 1024);                           \
            GLOAD_LDS(gl + u * 1024, dl + u * 1024);                           \
        }                                                                      \
    }

    // ---- scan: best-2 per row-slot (2 tiles x 4 slots, named regs) ----
    float bb00 = INFINITY, bb01 = INFINITY, bb02 = INFINITY, bb03 = INFINITY;
    float bb10 = INFINITY, bb11 = INFINITY, bb12 = INFINITY, bb13 = INFINITY;
    float ss00 = INFINITY, ss01 = INFINITY, ss02 = INFINITY, ss03 = INFINITY;
    float ss10 = INFINITY, ss11 = INFINITY, ss12 = INFINITY, ss13 = INFINITY;
    int   ii00 = 0, ii01 = 0, ii02 = 0, ii03 = 0;
    int   ii10 = 0, ii11 = 0, ii12 = 0, ii13 = 0;
#define UPD(S, B0, B1, I0) { float _s = (S);                                   \
        if (_s < B0) { B1 = B0; B0 = _s; I0 = j; } else B1 = fminf(B1, _s); }

    STAGE(0, 0);
    __syncthreads();   // vmcnt drain: chunk 0 visible
#pragma unroll 1
    for (int c = 0; c < 8; ++c) {
        if (c + 1 < 8) STAGE(c + 1, (c + 1) & 1);   // issue-early
        const bf16x8* sBh = reinterpret_cast<const bf16x8*>(&sB[c & 1][0][0]);
        const bf16x8* sBl = reinterpret_cast<const bf16x8*>(&sB[c & 1][1][0]);
#pragma unroll
        for (int ct8 = 0; ct8 < 8; ++ct8) {
            const int fb = ct8 * 128 + lane;
            bf16x8 vbh0 = sBh[fb], vbh1 = sBh[fb + 64];
            bf16x8 vbl0 = sBl[fb], vbl1 = sBl[fb + 64];
            const f32x4 z4 = {0.f, 0.f, 0.f, 0.f};
            // 12 INDEPENDENT MFMAs (no chained accumulators)
            f32x4 c0a = MFMA(a0h0, vbh0, z4);
            f32x4 c0b = MFMA(a0h1, vbh1, z4);
            f32x4 c1a = MFMA(a1h0, vbh0, z4);
            f32x4 c1b = MFMA(a1h1, vbh1, z4);
            f32x4 c0c = MFMA(a0h0, vbl0, z4);
            f32x4 c0d = MFMA(a0h1, vbl1, z4);
            f32x4 c1c = MFMA(a1h0, vbl0, z4);
            f32x4 c1d = MFMA(a1h1, vbl1, z4);
            f32x4 c0e = MFMA(a0l0, vbh0, z4);
            f32x4 c0f = MFMA(a0l1, vbh1, z4);
            f32x4 c1e = MFMA(a1l0, vbh0, z4);
            f32x4 c1f = MFMA(a1l1, vbh1, z4);
            f32x4 s0 = (c0a + c0b) + ((c0c + c0d) + (c0e + c0f));
            f32x4 s1 = (c1a + c1b) + ((c1c + c1d) + (c1e + c1f));
            const int j = (c * 8 + ct8) * 16 + m;
            const float hj = h[j];
            UPD(hj - s0[0], bb00, ss00, ii00)
            UPD(hj - s0[1], bb01, ss01, ii01)
            UPD(hj - s0[2], bb02, ss02, ii02)
            UPD(hj - s0[3], bb03, ss03, ii03)
            UPD(hj - s1[0], bb10, ss10, ii10)
            UPD(hj - s1[1], bb11, ss11, ii11)
            UPD(hj - s1[2], bb12, ss12, ii12)
            UPD(hj - s1[3], bb13, ss13, ii13)
        }
        __syncthreads();   // staged chunk c+1 visible; buf (c&1) reusable
    }
#undef STAGE
#undef UPD

    // ---- reduce best/2nd across the 16 col-lanes of each group ----
#pragma unroll
    for (int mask = 1; mask < 16; mask <<= 1) {
#define MRG(B0, I0, B1) { float ob0 = __shfl_xor(B0, mask); int oi = __shfl_xor(I0, mask); \
        float ob1 = __shfl_xor(B1, mask); \
        if (ob0 < B0) { B1 = fminf(fminf(B0, B1), ob1); B0 = ob0; I0 = oi; } \
        else { B1 = fminf(B1, fminf(ob0, ob1)); } }
        MRG(bb00, ii00, ss00) MRG(bb01, ii01, ss01)
        MRG(bb02, ii02, ss02) MRG(bb03, ii03, ss03)
        MRG(bb10, ii10, ss10) MRG(bb11, ii11, ss11)
        MRG(bb12, ii12, ss12) MRG(bb13, ii13, ss13)
#undef MRG
    }

    // ---- publish per-row results to LDS (m==0 lane of each group) ----
    if (m == 0) {
        sb0[w][g * 4 + 0] = bb00; sb1[w][g * 4 + 0] = ss00; sbi[w][g * 4 + 0] = ii00;
        sb0[w][g * 4 + 1] = bb01; sb1[w][g * 4 + 1] = ss01; sbi[w][g * 4 + 1] = ii01;
        sb0[w][g * 4 + 2] = bb02; sb1[w][g * 4 + 2] = ss02; sbi[w][g * 4 + 2] = ii02;
        sb0[w][g * 4 + 3] = bb03; sb1[w][g * 4 + 3] = ss03; sbi[w][g * 4 + 3] = ii03;
        sb0[w][16 + g * 4 + 0] = bb10; sb1[w][16 + g * 4 + 0] = ss10; sbi[w][16 + g * 4 + 0] = ii10;
        sb0[w][16 + g * 4 + 1] = bb11; sb1[w][16 + g * 4 + 1] = ss11; sbi[w][16 + g * 4 + 1] = ii11;
        sb0[w][16 + g * 4 + 2] = bb12; sb1[w][16 + g * 4 + 2] = ss12; sbi[w][16 + g * 4 + 2] = ii12;
        sb0[w][16 + g * 4 + 3] = bb13; sb1[w][16 + g * 4 + 3] = ss13; sbi[w][16 + g * 4 + 3] = ii13;
    }
    __syncthreads();

    // ---- epilogue: 2 lanes per row (rloc = lane>>1, q = lane&1) ----
    {
        const int rloc = lane >> 1, q = lane & 1;
        const int rowO = rowb32 + rloc;
        const float vb0 = sb0[w][rloc];
        const float vb1 = sb1[w][rloc];
        const int   vi  = sbi[w][rloc];
        const float Delta = 6e-8f * rsv[w][rloc] + 2.2e-5f;
        float local = 0.f;
        if (vb1 - vb0 <= Delta) {
            if (q == 0) { unsigned p = atomicAdd(flagN, 1u); flagL[p] = (unsigned)rowO; }
        } else {
            if (q == 0) { out_idx[rowO] = (float)vi; atomicAdd(&hist[vi], 1u); }
            const float4* cv = reinterpret_cast<const float4*>(cb + (size_t)vi * 64) + q * 8;
            const float4* zv = reinterpret_cast<const float4*>(z + (size_t)rowO * 64) + q * 8;
            float* orow = out_zq + (size_t)rowO * 64 + q * 32;
#pragma unroll
            for (int u = 0; u < 8; ++u) {
                float4 cc = cv[u], zo = zv[u];
                orow[4 * u + 0] = cc.x; orow[4 * u + 1] = cc.y;
                orow[4 * u + 2] = cc.z; orow[4 * u + 3] = cc.w;
                float dx = cc.x - zo.x, dy = cc.y - zo.y;
                float dz = cc.z - zo.z, dw = cc.w - zo.w;
                local = fmaf(dx, dx, local); local = fmaf(dy, dy, local);
                local = fmaf(dz, dz, local); local = fmaf(dw, dw, local);
            }
        }
#pragma unroll
        for (int off = 32; off; off >>= 1) local += __shfl_down(local, off);
        if (lane == 0) atomicAdd(sse, (double)local);
    }
}

// Exact re-scan for flagged rows: one wave per row, 16 codes per lane.
__global__ __launch_bounds__(64, 4) void k_cleanup(
    const float* __restrict__ z, const float* __restrict__ cb,
    const float* __restrict__ h,
    const unsigned* __restrict__ flagN, const unsigned* __restrict__ flagL,
    float* __restrict__ out_zq, float* __restrict__ out_idx,
    unsigned* __restrict__ hist, double* __restrict__ sse) {
    const unsigned n = *flagN;
    const int lane = threadIdx.x;

    for (unsigned f = blockIdx.x; f < n; f += gridDim.x) {
        const int row = (int)flagL[f];

        float tz[E_DIM];
        const float4* zp = reinterpret_cast<const float4*>(z + (size_t)row * 64);
#pragma unroll
        for (int k4 = 0; k4 < 16; ++k4) {
            float4 v = zp[k4];
            tz[4 * k4 + 0] = v.x; tz[4 * k4 + 1] = v.y;
            tz[4 * k4 + 2] = v.z; tz[4 * k4 + 3] = v.w;
        }
        const float nz = pw64_sq(tz);
#pragma unroll
        for (int k = 0; k < 64; ++k) tz[k] = 2.0f * tz[k];

        float bs = INFINITY;
        int bj = 0;
#pragma unroll 2
        for (int t = 0; t < 16; ++t) {
            const int j = lane + 64 * t;           // ascending j per lane
            const float4* cv = reinterpret_cast<const float4*>(cb + (size_t)j * 64);
            float mm = 0.f;
#pragma unroll
            for (int k4 = 0; k4 < 16; ++k4) {      // k ascending: exact chain
                float4 e = cv[k4];
                mm = fmaf(tz[4 * k4 + 0], e.x, mm);
                mm = fmaf(tz[4 * k4 + 1], e.y, mm);
                mm = fmaf(tz[4 * k4 + 2], e.z, mm);
                mm = fmaf(tz[4 * k4 + 3], e.w, mm);
            }
            float s = (nz + h[j]) - mm;
            if (s < bs) { bs = s; bj = j; }        // strict <: lowest j per lane
        }
#pragma unroll
        for (int off = 32; off; off >>= 1) {
            float s2 = __shfl_down(bs, off);
            int   j2 = __shfl_down(bj, off);
            if (s2 < bs || (s2 == bs && j2 < bj)) { bs = s2; bj = j2; }
        }
        bj = __shfl(bj, 0);

        float c = cb[(size_t)bj * 64 + lane];
        out_zq[(size_t)row * 64 + lane] = c;
        float d = c - 0.5f * tz[lane];
        float l2 = d * d;
#pragma unroll
        for (int off = 32; off; off >>= 1) l2 += __shfl_down(l2, off);
        if (lane == 0) {
            out_idx[row] = (float)bj;
            atomicAdd(&hist[bj], 1u);
            atomicAdd(sse, (double)l2);
        }
    }
}

// ---- round-5 fallback scan (used only if ws_size is too small) ----
__global__ __launch_bounds__(512, 2) void k_scan_fb(
    const float* __restrict__ z, const float* __restrict__ cb,
    const float* __restrict__ h,
    float* __restrict__ out_zq, float* __restrict__ out_idx,
    unsigned* __restrict__ hist, double* __restrict__ sse) {
    const int lane = threadIdx.x & 63;
    const int w = __builtin_amdgcn_readfirstlane(threadIdx.x >> 6);
    const int row = blockIdx.x * 64 + lane;
    float tz[E_DIM];
    const float4* zp = reinterpret_cast<const float4*>(z + (size_t)row * E_DIM);
#pragma unroll
    for (int k4 = 0; k4 < E_DIM / 4; ++k4) {
        float4 v = zp[k4];
        tz[4 * k4 + 0] = v.x; tz[4 * k4 + 1] = v.y;
        tz[4 * k4 + 2] = v.z; tz[4 * k4 + 3] = v.w;
    }
    const float nz = pw64_sq(tz);
#pragma unroll
    for (int k = 0; k < E_DIM; ++k) tz[k] = 2.0f * tz[k];
    float b0 = INFINITY; int bi = 0;
    const int j0 = w * 128;
#pragma unroll 1
    for (int j = j0; j < j0 + 128; j += 4) {
        const float* c0 = cb + (size_t)j * E_DIM;
        float m0 = 0.f, m1 = 0.f, m2 = 0.f, m3 = 0.f;
#pragma unroll
        for (int k = 0; k < E_DIM; ++k) {
            float wk = tz[k];
            m0 = fmaf(wk, c0[0 * E_DIM + k], m0);
            m1 = fmaf(wk, c0[1 * E_DIM + k], m1);
            m2 = fmaf(wk, c0[2 * E_DIM + k], m2);
            m3 = fmaf(wk, c0[3 * E_DIM + k], m3);
        }
        float s0 = (nz + h[j + 0]) - m0;
        float s1 = (nz + h[j + 1]) - m1;
        float s2 = (nz + h[j + 2]) - m2;
        float s3 = (nz + h[j + 3]) - m3;
        if (s0 < b0) { b0 = s0; bi = j + 0; }
        if (s1 < b0) { b0 = s1; bi = j + 1; }
        if (s2 < b0) { b0 = s2; bi = j + 2; }
        if (s3 < b0) { b0 = s3; bi = j + 3; }
    }
    __shared__ float lb[8][64];
    __shared__ int   li[8][64];
    lb[w][lane] = b0; li[w][lane] = bi;
    __syncthreads();
    if (threadIdx.x < 64) {
        float b = lb[0][lane]; int i = li[0][lane];
#pragma unroll
        for (int c = 1; c < 8; ++c) {
            float bc = lb[c][lane]; int ic = li[c][lane];
            if (bc < b) { b = bc; i = ic; }
        }
        out_idx[row] = (float)i;
        float local = 0.f;
        const float4* cv = reinterpret_cast<const float4*>(cb + (size_t)i * E_DIM);
        float* orow = out_zq + (size_t)row * E_DIM;
#pragma unroll
        for (int k4 = 0; k4 < E_DIM / 4; ++k4) {
            float4 c = cv[k4];
            float zx = 0.5f * tz[4 * k4 + 0], zy = 0.5f * tz[4 * k4 + 1];
            float zz = 0.5f * tz[4 * k4 + 2], zw = 0.5f * tz[4 * k4 + 3];
            orow[4 * k4 + 0] = c.x; orow[4 * k4 + 1] = c.y;
            orow[4 * k4 + 2] = c.z; orow[4 * k4 + 3] = c.w;
            float dx = c.x - zx, dy = c.y - zy, dz = c.z - zz, dw = c.w - zw;
            local = fmaf(dx, dx, local); local = fmaf(dy, dy, local);
            local = fmaf(dz, dz, local); local = fmaf(dw, dw, local);
        }
        atomicAdd(&hist[i], 1u);
#pragma unroll
        for (int off = 32; off; off >>= 1) local += __shfl_down(local, off);
        if (lane == 0) atomicAdd(sse, (double)local);
    }
}

__global__ __launch_bounds__(256) void k_final(
    const unsigned* __restrict__ hist, const double* __restrict__ sse,
    float* __restrict__ out, int nrows) {
    __shared__ double sh[256];
    double acc = 0.0;
    for (int j = threadIdx.x; j < N_E; j += 256) {
        double p = (double)hist[j] / (double)nrows;
        acc += p * log(p + 1e-10);
    }
    sh[threadIdx.x] = acc;
    __syncthreads();
    for (int s = 128; s; s >>= 1) {
        if (threadIdx.x < s) sh[threadIdx.x] += sh[threadIdx.x + s];
        __syncthreads();
    }
    if (threadIdx.x == 0) {
        double ntot = (double)nrows * (double)E_DIM;
        out[0] = (float)((1.0 + BETA) * (*sse) / ntot);               // loss
        out[1 + (size_t)nrows * E_DIM] = (float)exp(-sh[0]);          // perplexity
    }
}

extern "C" void kernel_launch(void* const* d_in, const int* in_sizes, int n_in,
                              void* d_out, int out_size, void* d_ws, size_t ws_size,
                              hipStream_t stream) {
    const float* z  = (const float*)d_in[0];
    const float* cb = (const float*)d_in[1];
    const int nrows = in_sizes[0] / E_DIM;   // 65536
    float* out = (float*)d_out;

    char* ws = (char*)d_ws;
    unsigned* hist  = (unsigned*)(ws + 0);
    double*   sse   = (double*)  (ws + 4096);
    unsigned* flagN = (unsigned*)(ws + 4104);
    float*    h     = (float*)   (ws + 4112);
    unsigned short* ebh = (unsigned short*)(ws + 8208);
    unsigned short* ebl = (unsigned short*)(ws + 139280);
    unsigned* flagL = (unsigned*)(ws + 270352);
    // end of ws use: 270352 + 262144 = 532496 bytes

    float* out_zq  = out + 1;
    float* out_idx = out + 1 + (size_t)nrows * E_DIM + 1;

    hipMemsetAsync(d_ws, 0, 4112, stream);  // hist + sse + flagN
    k_h<<<(N_E + 255) / 256, 256, 0, stream>>>(cb, h);

    if (ws_size >= 532496) {
        k_prep<<<256, 256, 0, stream>>>(cb, ebh, ebl);
        k_mfma<<<nrows / 128, 256, 0, stream>>>(z, cb, h, ebh, ebl,
                                                out_zq, out_idx, hist, sse, flagN, flagL);
        k_cleanup<<<2048, 64, 0, stream>>>(z, cb, h, flagN, flagL,
                                           out_zq, out_idx, hist, sse);
    } else {
        k_scan_fb<<<nrows / 64, 512, 0, stream>>>(z, cb, h, out_zq, out_idx, hist, sse);
    }
    k_final<<<1, 256, 0, stream>>>(hist, sse, out, nrows);
}